// Round 2
// baseline (208.321 us; speedup 1.0000x reference)
//
#include <hip/hip_runtime.h>

// ALSTM: adaptive-computation-time LSTM (halts at t=1 for this data; exact
// for general n).
// R13: occupancy restructure. Theory: limiter is per-CU memory parallelism
// (9.5 GB/s/CU effective), pinned by the 148 KB W_hh-bf16 LDS stage forcing
// 1 block/CU. The stage served a matvec that runs ONCE (halt at t=1).
//  - W_hh LDS stage DELETED. t=0 gate dot fused into the prologue fp32
//    stream (h0 known pre-sync); t>=1 matvec reads W_hh fp32 from global
//    (L2/L3-resident after prologue).
//  - NBLK=512, JPB=4, 2 blocks/CU, 16 waves/CU, VGPR<=128 via
//    __launch_bounds__(512,4). LDS ~21 KB/block.
//  - All-fp32 datapath (bf16 gone) -> better absmax too.
//  - Grid sync unchanged (proven); 512 arrive/mail slots now.

#define HID    2048
#define INS    1024
#define OUTS   1024
#define MSTEPS 100
#define NBLK   512
#define NTHR   512
#define NWAVE  8
#define JPB    4      // hidden units owned per block (512*4 = 2048)
#define RPB    16     // gate rows per block (4 gates * JPB)
#define SLOTF  16     // floats per sync slot (64 B)

typedef unsigned long long u64;
typedef unsigned int u32;

__device__ __forceinline__ float wave_allreduce(float v) {
    #pragma unroll
    for (int off = 32; off > 0; off >>= 1)
        v += __shfl_xor(v, off, 64);
    return v;  // all lanes hold the sum
}

__device__ __forceinline__ u64 pack_tag(unsigned tag, float v) {
    return ((u64)tag << 32) | (u64)__float_as_uint(v);
}
__device__ __forceinline__ u64 aload(const u64* p) {
    return __hip_atomic_load(p, __ATOMIC_RELAXED, __HIP_MEMORY_SCOPE_AGENT);
}
__device__ __forceinline__ void astore(u64* p, u64 v) {
    __hip_atomic_store(p, v, __ATOMIC_RELAXED, __HIP_MEMORY_SCOPE_AGENT);
}

// ws layout (floats): [0..8192) arrive slots (512 x 64B) | [8192..16384)
// mailboxes | [16384..18432) hbuf0 | [18432..20480) hbuf1.
// kernel_launch zeroes the first 65536 bytes each call.

__global__ __launch_bounds__(NTHR, 4) void alstm_kernel(
    const float* __restrict__ x,      const float* __restrict__ h0,
    const float* __restrict__ c0,     const float* __restrict__ W_ih,
    const float* __restrict__ b_ih,   const float* __restrict__ W_hh,
    const float* __restrict__ b_hh,   const float* __restrict__ w_halt,
    const float* __restrict__ b_halt, const float* __restrict__ W_out,
    const float* __restrict__ b_out,  float* __restrict__ out,
    float* __restrict__ ws)
{
    const int b    = blockIdx.x;
    const int tid  = threadIdx.x;
    const int wave = tid >> 6;
    const int lane = tid & 63;

    float* arrive = ws;                 // 512 x SLOTF floats
    float* mail   = ws + NBLK * SLOTF;
    float* hbuf0  = ws + 2 * NBLK * SLOTF;
    float* hbuf1  = hbuf0 + HID;

    __shared__ float hcur[HID];           // 8 KB: h_t broadcast for matvec
    __shared__ float x_lds[INS];          // 4 KB
    __shared__ float hjoint[HID];         // 8 KB: h0 fp32, then hbar accum
    __shared__ float gate_lds[RPB];
    __shared__ float ihx_lds[RPB];
    __shared__ float red_lds[NWAVE];
    __shared__ float bcast_lds;
    __shared__ float psum[NWAVE];

    const int j_own = b * JPB + tid;      // valid when tid < JPB
    const int lr0   = 2 * wave;           // this wave's first gate row (of 16)
    const int r0    = (lr0 >> 2) * HID + b * JPB + (lr0 & 3);
    const int r1    = ((lr0 + 1) >> 2) * HID + b * JPB + ((lr0 + 1) & 3);

    #define SYNC_ROUND(tag_, part_, dot_) do {                                 \
        if (tid == 0) {                                                        \
            __threadfence();   /* wb: h stores reach coherence point */        \
            astore((u64*)(arrive + SLOTF * b), pack_tag((tag_), (part_)));     \
        }                                                                      \
        if (b == 0) {                                                          \
            float pf = 0.f;                                                    \
            {                                                                  \
                u64 v = aload((u64*)(arrive + SLOTF * tid));                   \
                while ((unsigned)(v >> 32) != (unsigned)(tag_)) {              \
                    __builtin_amdgcn_s_sleep(1);                               \
                    v = aload((u64*)(arrive + SLOTF * tid));                   \
                }                                                              \
                pf = __uint_as_float((unsigned)v);                             \
            }                                                                  \
            float s = wave_allreduce(pf);                                      \
            if (lane == 0) red_lds[wave] = s;                                  \
            __syncthreads();                                                   \
            if (tid == 0) {                                                    \
                float tt = 0.f;                                                \
                _Pragma("unroll")                                              \
                for (int w_ = 0; w_ < NWAVE; ++w_) tt += red_lds[w_];          \
                bcast_lds = tt;                                                \
            }                                                                  \
            __syncthreads();                                                   \
            astore((u64*)(mail + SLOTF * tid), pack_tag((tag_), bcast_lds));   \
        }                                                                      \
        if (tid == 0) {                                                        \
            u64 v = aload((u64*)(mail + SLOTF * b));                           \
            while ((unsigned)(v >> 32) != (unsigned)(tag_)) {                  \
                __builtin_amdgcn_s_sleep(1);                                   \
                v = aload((u64*)(mail + SLOTF * b));                           \
            }                                                                  \
            bcast_lds = __uint_as_float((unsigned)v);                          \
            __threadfence();   /* inv: later plain reads see fresh data */     \
        }                                                                      \
        __syncthreads();                                                       \
        (dot_) = bcast_lds;                                                    \
    } while (0)

    // ---------------- prologue: one continuous stream ----------------
    const float bh = b_halt[0];
    float2 xv  = ((const float2*)x)[tid];
    float4 h0v = ((const float4*)h0)[tid];
    float c_reg = (tid < JPB) ? c0[j_own]     : 0.f;
    float whv   = (tid < JPB) ? w_halt[j_own] : 0.f;
    float bo    = (tid < 2)   ? b_out[b * 2 + tid] : 0.f;
    float bsum = 0.f, wflg = 0.f;
    if (lane < 2) {
        const int lr = lr0 + lane;
        const int r  = (lr >> 2) * HID + b * JPB + (lr & 3);
        bsum = b_ih[r] + b_hh[r];
        wflg = W_ih[(size_t)r * (INS + 1)];
    }
    __builtin_amdgcn_sched_barrier(0);   // small loads pinned oldest

    // W_ih: 2 rows x 4 float4/lane, issued now
    const float*  wr_[2];
    const float4* wv_[2];
    int p0_[2];
    #pragma unroll
    for (int rr = 0; rr < 2; ++rr) {
        const int lr = lr0 + rr;
        const int r  = (lr >> 2) * HID + b * JPB + (lr & 3);
        wr_[rr] = W_ih + (size_t)r * (INS + 1) + 1;   // payload
        p0_[rr] = (4 - ((r + 1) & 3)) & 3;
        wv_[rr] = (const float4*)(wr_[rr] + p0_[rr]);
    }
    float4 iw0[4], iw1[4];
    #pragma unroll
    for (int ii = 0; ii < 4; ++ii) {
        const int i  = lane + 64 * ii;
        const int ic = (i < 255) ? i : 0;   // clamp; masked at accumulate
        iw0[ii] = wv_[0][ic];
        iw1[ii] = wv_[1][ic];
    }

    // W_hh row r0: 8 float4/lane, issued now
    float4 wa[8];
    {
        const float4* src = (const float4*)(W_hh + (size_t)r0 * HID);
        #pragma unroll
        for (int m = 0; m < 8; ++m) wa[m] = src[lane + 64 * m];
    }

    // W_out: this wave's quarter-row (2 float4/lane), kept to epilogue
    const int orow = b * 2 + (wave & 1);
    const int oq   = wave >> 1;           // quarter 0..3
    const float4* wrp = (const float4*)(W_out + (size_t)orow * HID) + oq * 128;
    float4 wo0 = wrp[lane], wo1 = wrp[lane + 64];

    __builtin_amdgcn_sched_barrier(0);   // keep the burst in flight

    // stage x + h0 (oldest loads; burst stays outstanding past the waitcnt)
    ((float2*)x_lds)[tid]  = xv;
    ((float4*)hjoint)[tid] = h0v;        // hjoint = fp32 h0 for fused t=0 dot
    __syncthreads();

    // ---- ih dots: W_ih[:,1:]@x, 2 rows ----
    float a0 = 0.f, a1 = 0.f;
    #pragma unroll
    for (int ii = 0; ii < 4; ++ii) {
        const int   i   = lane + 64 * ii;
        const int   ic  = (i < 255) ? i : 0;
        const float msk = (i < 255) ? 1.f : 0.f;
        {
            float4 w4 = iw0[ii];
            const int k = p0_[0] + 4 * ic;
            a0 += msk * (w4.x * x_lds[k]     + w4.y * x_lds[k + 1]
                       + w4.z * x_lds[k + 2] + w4.w * x_lds[k + 3]);
        }
        {
            float4 w4 = iw1[ii];
            const int k = p0_[1] + 4 * ic;
            a1 += msk * (w4.x * x_lds[k]     + w4.y * x_lds[k + 1]
                       + w4.z * x_lds[k + 2] + w4.w * x_lds[k + 3]);
        }
    }
    // leftover 4 elements per row: lanes 0..3, one element each
    if (lane < 4) {
        #pragma unroll
        for (int rr = 0; rr < 2; ++rr) {
            const int p0 = p0_[rr];
            const int e  = (lane < p0) ? lane : 1020 + lane;
            float s = wr_[rr][e] * x_lds[e];
            if (rr == 0) a0 += s; else a1 += s;
        }
    }

    // issue W_hh row r1 (reuses iw registers, now dead)
    float4 wb[8];
    {
        const float4* src = (const float4*)(W_hh + (size_t)r1 * HID);
        #pragma unroll
        for (int m = 0; m < 8; ++m) wb[m] = src[lane + 64 * m];
    }

    // ---- t=0 W_hh gate dots: fp32 x fp32 vs h0 (hjoint) ----
    float g0 = 0.f, g1 = 0.f;
    {
        const float4* h4 = (const float4*)hjoint;
        #pragma unroll
        for (int m = 0; m < 8; ++m) {
            float4 hh = h4[lane + 64 * m];
            float4 w4 = wa[m];
            g0 += w4.x * hh.x + w4.y * hh.y + w4.z * hh.z + w4.w * hh.w;
        }
        #pragma unroll
        for (int m = 0; m < 8; ++m) {
            float4 hh = h4[lane + 64 * m];
            float4 w4 = wb[m];
            g1 += w4.x * hh.x + w4.y * hh.y + w4.z * hh.z + w4.w * hh.w;
        }
    }

    a0 = wave_allreduce(a0); a1 = wave_allreduce(a1);
    g0 = wave_allreduce(g0); g1 = wave_allreduce(g1);
    if (lane < 2) {
        float av = lane ? a1 : a0;
        float gv = lane ? g1 : g0;
        ihx_lds[lr0 + lane]  = av + bsum;                // reused every step
        gate_lds[lr0 + lane] = av + bsum + wflg + gv;    // t=0 gates (flag=1)
    }
    __syncthreads();                       // gate_lds ready; hjoint reads done
    ((float4*)hjoint)[tid] = make_float4(0.f, 0.f, 0.f, 0.f);  // hbar accum
    // (per-thread slot: only this thread touches hjoint[4*tid..4*tid+3]
    //  until the epilogue barrier)

    // ------------- recurrence -------------
    float h_reg = 0.f, cbar = 0.f;
    float csum = 0.f, r_halt = 0.f;
    int   n_halt = 0;
    for (int t = 0; t <= MSTEPS; ++t) {
        // gate_lds valid here (pre-loop sync for t=0; bottom sync for t>0)
        float part = 0.f;
        float* hdst = (t & 1) ? hbuf1 : hbuf0;
        if (tid < JPB) {
            float iv = gate_lds[0 * JPB + tid];
            float fv = gate_lds[1 * JPB + tid];
            float gv = gate_lds[2 * JPB + tid];
            float ov = gate_lds[3 * JPB + tid];
            iv = 1.f / (1.f + expf(-iv));
            fv = 1.f / (1.f + expf(-fv));
            gv = tanhf(gv);
            ov = 1.f / (1.f + expf(-ov));
            c_reg = fv * c_reg + iv * gv;
            h_reg = ov * tanhf(c_reg);
            hdst[j_own] = h_reg;
            part = h_reg * whv;
        }
        part += __shfl_down(part, 2, 64);
        part += __shfl_down(part, 1, 64);

        float dotv;
        SYNC_ROUND(t + 1, part, dotv);

        float p = 1.f / (1.f + expf(-(dotv + bh)));
        float prev = csum;
        csum += p;
        bool  halt_now = (csum >= 1.f - 0.01f) || (t == MSTEPS);
        float wt = halt_now ? (1.f - prev) : p;

        // full h_{t+1}: one read serves hbar accumulation AND hcur staging
        float4 hv = ((const float4*)hdst)[tid];
        float4 hb = ((float4*)hjoint)[tid];      // own slot, no race
        hb.x += wt * hv.x; hb.y += wt * hv.y;
        hb.z += wt * hv.z; hb.w += wt * hv.w;
        ((float4*)hjoint)[tid] = hb;
        if (tid < JPB) cbar += wt * c_reg;
        if (halt_now) { n_halt = t; r_halt = 1.f - prev; break; }  // uniform

        ((float4*)hcur)[tid] = hv;
        __syncthreads();                         // hcur ready

        {   // W_hh @ h : fp32 from global (L2/L3-resident), h from LDS
            const float4* w0p = (const float4*)(W_hh + (size_t)r0 * HID);
            const float4* w1p = (const float4*)(W_hh + (size_t)r1 * HID);
            const float4* hc4 = (const float4*)hcur;
            float m0 = 0.f, m1 = 0.f;
            #pragma unroll
            for (int m = 0; m < 8; ++m) {
                float4 wA = w0p[lane + 64 * m];
                float4 wB = w1p[lane + 64 * m];
                float4 hh = hc4[lane + 64 * m];
                m0 += wA.x * hh.x + wA.y * hh.y + wA.z * hh.z + wA.w * hh.w;
                m1 += wB.x * hh.x + wB.y * hh.y + wB.z * hh.z + wB.w * hh.w;
            }
            m0 = wave_allreduce(m0);
            m1 = wave_allreduce(m1);
            if (lane < 2) {
                float mv = lane ? m1 : m0;
                gate_lds[lr0 + lane] = ihx_lds[lr0 + lane] + mv;
            }
        }
        __syncthreads();                         // gate_lds ready for next t
    }

    // ------------- epilogue: no grid sync needed -------------
    __syncthreads();                             // hbar (hjoint) complete
    if (tid < JPB) {
        out[OUTS + j_own]       = hjoint[j_own];   // h_out
        out[OUTS + HID + j_own] = cbar;            // c_out
    }
    if (b == 0 && tid == 0) out[OUTS + 2 * HID] = (float)(n_halt + 1) + r_halt;

    // output = W_out @ hbar + b_out : W_out quarter-rows already in registers
    {
        const float4* hb4 = (const float4*)hjoint + oq * 128;
        float acc = 0.f;
        { float4 h4 = hb4[lane];      acc += wo0.x*h4.x + wo0.y*h4.y + wo0.z*h4.z + wo0.w*h4.w; }
        { float4 h4 = hb4[lane + 64]; acc += wo1.x*h4.x + wo1.y*h4.y + wo1.z*h4.z + wo1.w*h4.w; }
        acc = wave_allreduce(acc);
        if (lane == 0) psum[wave] = acc;
    }
    __syncthreads();
    if (tid < 2)
        out[b * 2 + tid] = psum[tid] + psum[tid + 2] + psum[tid + 4]
                         + psum[tid + 6] + bo;

    #undef SYNC_ROUND
}

extern "C" void kernel_launch(void* const* d_in, const int* in_sizes, int n_in,
                              void* d_out, int out_size, void* d_ws, size_t ws_size,
                              hipStream_t stream) {
    const float* x      = (const float*)d_in[0];
    const float* h0     = (const float*)d_in[1];
    const float* c0     = (const float*)d_in[2];
    const float* W_ih   = (const float*)d_in[3];
    const float* b_ih   = (const float*)d_in[4];
    const float* W_hh   = (const float*)d_in[5];
    const float* b_hh   = (const float*)d_in[6];
    const float* w_halt = (const float*)d_in[7];
    const float* b_halt = (const float*)d_in[8];
    const float* W_out  = (const float*)d_in[9];
    const float* b_out  = (const float*)d_in[10];
    float* out = (float*)d_out;
    float* ws  = (float*)d_ws;

    // Zero arrive slots + mailboxes (ws is poisoned 0xAA by the harness).
    hipMemsetAsync(d_ws, 0, 65536, stream);

    alstm_kernel<<<dim3(NBLK), dim3(NTHR), 0, stream>>>(
        x, h0, c0, W_ih, b_ih, W_hh, b_hh, w_halt, b_halt, W_out, b_out,
        out, ws);
}

// Round 3
// 167.834 us; speedup vs baseline: 1.2412x; 1.2412x over previous
//
#include <hip/hip_runtime.h>

// ALSTM: adaptive-computation-time LSTM (halts at t=1 for this data; exact
// for general n).
// R14: register-resident W_hh at 1 block/CU.
//  - At 2 waves/SIMD the VGPR cap is 256/wave => 512 KB regs/CU. Per-CU
//    W_hh share (NBLK=256) is 262 KB = 128 VGPR/thread. W_hh is loaded
//    ONCE into registers (no LDS stage, no bf16 convert, no drain, no
//    re-read) and held across the grid syncs.
//  - amdgpu_waves_per_eu(2,2) pins the allocator budget at 256 VGPR so it
//    cannot repeat R13's clamp-to-64-and-spill (WRITE_SIZE 3.4 MB).
//  - Issue order == consume order (smalls, W_ih, W_hh, W_out) so vmcnt
//    waits are tight; ~60 loads/lane in flight through the prologue.
//  - All-fp32 datapath (absmax ~1e-6, per R13).
//  - Grid sync + halting logic unchanged (proven).

#define HID    2048
#define INS    1024
#define OUTS   1024
#define MSTEPS 100
#define NBLK   256
#define NTHR   512
#define NWAVE  8
#define JPB    8      // hidden units owned per block (256*8 = 2048)
#define RPB    32     // gate rows per block (4 gates * JPB)
#define SLOTF  16     // floats per sync slot (64 B)

typedef unsigned long long u64;
typedef unsigned int u32;

__device__ __forceinline__ float wave_allreduce(float v) {
    #pragma unroll
    for (int off = 32; off > 0; off >>= 1)
        v += __shfl_xor(v, off, 64);
    return v;  // all lanes hold the sum
}

__device__ __forceinline__ u64 pack_tag(unsigned tag, float v) {
    return ((u64)tag << 32) | (u64)__float_as_uint(v);
}
__device__ __forceinline__ u64 aload(const u64* p) {
    return __hip_atomic_load(p, __ATOMIC_RELAXED, __HIP_MEMORY_SCOPE_AGENT);
}
__device__ __forceinline__ void astore(u64* p, u64 v) {
    __hip_atomic_store(p, v, __ATOMIC_RELAXED, __HIP_MEMORY_SCOPE_AGENT);
}

// ws layout (floats): [0..4096) arrive slots (256 x 64B) | [4096..8192)
// mailboxes | [8192..10240) hbuf0 | [10240..12288) hbuf1.
// kernel_launch zeroes the first 32768 bytes each call.

__global__
__attribute__((amdgpu_flat_work_group_size(NTHR, NTHR)))
__attribute__((amdgpu_waves_per_eu(2, 2)))
void alstm_kernel(
    const float* __restrict__ x,      const float* __restrict__ h0,
    const float* __restrict__ c0,     const float* __restrict__ W_ih,
    const float* __restrict__ b_ih,   const float* __restrict__ W_hh,
    const float* __restrict__ b_hh,   const float* __restrict__ w_halt,
    const float* __restrict__ b_halt, const float* __restrict__ W_out,
    const float* __restrict__ b_out,  float* __restrict__ out,
    float* __restrict__ ws)
{
    const int b    = blockIdx.x;
    const int tid  = threadIdx.x;
    const int wave = tid >> 6;
    const int lane = tid & 63;

    float* arrive = ws;                 // 256 x SLOTF floats
    float* mail   = ws + NBLK * SLOTF;
    float* hbuf0  = ws + 2 * NBLK * SLOTF;
    float* hbuf1  = hbuf0 + HID;

    __shared__ float x_lds[INS];          // 4 KB
    __shared__ float hjoint[HID];         // 8 KB: h0 fp32, then hbar accum
    __shared__ float hcur[HID];           // 8 KB: h_t broadcast for matvec
    __shared__ float gate_lds[RPB];
    __shared__ float ihx_lds[RPB];
    __shared__ float red_lds[4];
    __shared__ float bcast_lds;
    __shared__ float psum[NWAVE];

    const int j_own = b * JPB + tid;      // valid when tid < JPB
    const int lr0   = 4 * wave;           // rows lr0..lr0+3 ; lr = gate*8+unit
    const int rbase = (lr0 >> 3) * HID + b * JPB + (lr0 & 7);

    #define SYNC_ROUND(tag_, part_, dot_) do {                                 \
        if (tid == 0) {                                                        \
            __threadfence();   /* wb: h stores reach coherence point */        \
            astore((u64*)(arrive + SLOTF * b), pack_tag((tag_), (part_)));     \
        }                                                                      \
        if (b == 0) {                                                          \
            float pf = 0.f;                                                    \
            if (tid < NBLK) {                                                  \
                u64 v = aload((u64*)(arrive + SLOTF * tid));                   \
                while ((unsigned)(v >> 32) != (unsigned)(tag_)) {              \
                    __builtin_amdgcn_s_sleep(1);                               \
                    v = aload((u64*)(arrive + SLOTF * tid));                   \
                }                                                              \
                pf = __uint_as_float((unsigned)v);                             \
            }                                                                  \
            float s = wave_allreduce(pf);                                      \
            if (lane == 0 && wave < 4) red_lds[wave] = s;                      \
            __syncthreads();                                                   \
            if (tid == 0)                                                      \
                bcast_lds = red_lds[0] + red_lds[1] + red_lds[2] + red_lds[3]; \
            __syncthreads();                                                   \
            if (tid < NBLK)                                                    \
                astore((u64*)(mail + SLOTF * tid), pack_tag((tag_), bcast_lds)); \
        }                                                                      \
        if (tid == 0) {                                                        \
            u64 v = aload((u64*)(mail + SLOTF * b));                           \
            while ((unsigned)(v >> 32) != (unsigned)(tag_)) {                  \
                __builtin_amdgcn_s_sleep(1);                                   \
                v = aload((u64*)(mail + SLOTF * b));                           \
            }                                                                  \
            bcast_lds = __uint_as_float((unsigned)v);                          \
            __threadfence();   /* inv: later plain reads see fresh data */     \
        }                                                                      \
        __syncthreads();                                                       \
        (dot_) = bcast_lds;                                                    \
    } while (0)

    // W_hh@h dot: 4 rows (register-resident) vs a fp32 vector in LDS.
    #define DOT4(H4P, G0, G1, G2, G3) do {                                     \
        const float4* h4__ = (H4P);                                            \
        _Pragma("unroll")                                                      \
        for (int m = 0; m < 8; ++m) {                                          \
            float4 hh = h4__[lane + 64 * m];                                   \
            G0 += wa0[m].x*hh.x + wa0[m].y*hh.y + wa0[m].z*hh.z + wa0[m].w*hh.w; \
            G1 += wa1[m].x*hh.x + wa1[m].y*hh.y + wa1[m].z*hh.z + wa1[m].w*hh.w; \
            G2 += wa2[m].x*hh.x + wa2[m].y*hh.y + wa2[m].z*hh.z + wa2[m].w*hh.w; \
            G3 += wa3[m].x*hh.x + wa3[m].y*hh.y + wa3[m].z*hh.z + wa3[m].w*hh.w; \
        }                                                                      \
    } while (0)

    // ---------------- Group A: smalls (oldest in the queue) ----------------
    const float bh = b_halt[0];
    float2 xv  = ((const float2*)x)[tid];
    float4 h0v = ((const float4*)h0)[tid];
    float c_reg = (tid < JPB) ? c0[j_own]     : 0.f;
    float whv   = (tid < JPB) ? w_halt[j_own] : 0.f;
    float bo    = (tid < 4)   ? b_out[b * 4 + tid] : 0.f;
    float bsum = 0.f, wflg = 0.f;
    if (lane < 4) {
        const int lr = lr0 + lane;
        const int r  = (lr >> 3) * HID + b * JPB + (lr & 7);
        bsum = b_ih[r] + b_hh[r];
        wflg = W_ih[(size_t)r * (INS + 1)];
    }
    __builtin_amdgcn_sched_barrier(0);

    // ---------------- Group B: W_ih 4 rows x 4 float4 ----------------
    const float*  wr_[4];
    const float4* wv_[4];
    int p0_[4];
    #pragma unroll
    for (int rr = 0; rr < 4; ++rr) {
        const int lr = lr0 + rr;
        const int r  = (lr >> 3) * HID + b * JPB + (lr & 7);
        wr_[rr] = W_ih + (size_t)r * (INS + 1) + 1;   // payload
        p0_[rr] = (4 - ((r + 1) & 3)) & 3;
        wv_[rr] = (const float4*)(wr_[rr] + p0_[rr]);
    }
    float4 iw0[4], iw1[4], iw2[4], iw3[4];
    #pragma unroll
    for (int ii = 0; ii < 4; ++ii) {
        const int i  = lane + 64 * ii;
        const int ic = (i < 255) ? i : 0;   // clamp; masked at accumulate
        iw0[ii] = wv_[0][ic];
        iw1[ii] = wv_[1][ic];
        iw2[ii] = wv_[2][ic];
        iw3[ii] = wv_[3][ic];
    }
    __builtin_amdgcn_sched_barrier(0);

    // ------- Group C: W_hh 4 rows x 8 float4 -> registers (128 VGPR) -------
    float4 wa0[8], wa1[8], wa2[8], wa3[8];
    {
        const float4* s0 = (const float4*)(W_hh + (size_t)(rbase + 0) * HID);
        const float4* s1 = (const float4*)(W_hh + (size_t)(rbase + 1) * HID);
        const float4* s2 = (const float4*)(W_hh + (size_t)(rbase + 2) * HID);
        const float4* s3 = (const float4*)(W_hh + (size_t)(rbase + 3) * HID);
        #pragma unroll
        for (int m = 0; m < 8; ++m) {
            wa0[m] = s0[lane + 64 * m];
            wa1[m] = s1[lane + 64 * m];
            wa2[m] = s2[lane + 64 * m];
            wa3[m] = s3[lane + 64 * m];
        }
    }
    __builtin_amdgcn_sched_barrier(0);

    // ------- Group D: W_out 4 float4 (half-row per wave) -> registers -------
    const int orow  = b * 4 + (wave & 3);
    const int ohalf = wave >> 2;
    const float4* wrow = (const float4*)(W_out + (size_t)orow * HID) + ohalf * 256;
    float4 wo0 = wrow[lane], wo1 = wrow[lane + 64],
           wo2 = wrow[lane + 128], wo3 = wrow[lane + 192];
    __builtin_amdgcn_sched_barrier(0);

    // stage x + h0 (waits only on Group A; B/C/D stay in flight)
    ((float2*)x_lds)[tid]  = xv;
    ((float4*)hjoint)[tid] = h0v;        // hjoint = fp32 h0 for fused t=0 dot
    __syncthreads();

    // ---- x-dots: W_ih[:,1:]@x, 4 rows (consumes Group B) ----
    float a0 = 0.f, a1 = 0.f, a2 = 0.f, a3 = 0.f;
    #pragma unroll
    for (int ii = 0; ii < 4; ++ii) {
        const int   i   = lane + 64 * ii;
        const int   ic  = (i < 255) ? i : 0;
        const float msk = (i < 255) ? 1.f : 0.f;
        #pragma unroll
        for (int rr = 0; rr < 4; ++rr) {
            float4 w4 = (rr == 0) ? iw0[ii] : (rr == 1) ? iw1[ii]
                      : (rr == 2) ? iw2[ii] : iw3[ii];
            const int k = p0_[rr] + 4 * ic;
            float s = w4.x * x_lds[k]     + w4.y * x_lds[k + 1]
                    + w4.z * x_lds[k + 2] + w4.w * x_lds[k + 3];
            s *= msk;
            if      (rr == 0) a0 += s;
            else if (rr == 1) a1 += s;
            else if (rr == 2) a2 += s;
            else              a3 += s;
        }
    }
    if (lane < 4) {   // leftover 4 elements per row
        #pragma unroll
        for (int rr = 0; rr < 4; ++rr) {
            const int p0 = p0_[rr];
            const int e  = (lane < p0) ? lane : 1020 + lane;
            float s = wr_[rr][e] * x_lds[e];
            if      (rr == 0) a0 += s;
            else if (rr == 1) a1 += s;
            else if (rr == 2) a2 += s;
            else              a3 += s;
        }
    }

    // ---- t=0 gate dots: register W_hh vs fp32 h0 (consumes Group C) ----
    float g0 = 0.f, g1 = 0.f, g2 = 0.f, g3 = 0.f;
    DOT4((const float4*)hjoint, g0, g1, g2, g3);

    a0 = wave_allreduce(a0); a1 = wave_allreduce(a1);
    a2 = wave_allreduce(a2); a3 = wave_allreduce(a3);
    g0 = wave_allreduce(g0); g1 = wave_allreduce(g1);
    g2 = wave_allreduce(g2); g3 = wave_allreduce(g3);
    if (lane < 4) {
        float av = (lane == 0) ? a0 : (lane == 1) ? a1 : (lane == 2) ? a2 : a3;
        float gv = (lane == 0) ? g0 : (lane == 1) ? g1 : (lane == 2) ? g2 : g3;
        ihx_lds[lr0 + lane]  = av + bsum;                // reused every step
        gate_lds[lr0 + lane] = av + bsum + wflg + gv;    // t=0 gates (flag=1)
    }
    __syncthreads();                       // gate_lds ready; hjoint reads done
    ((float4*)hjoint)[tid] = make_float4(0.f, 0.f, 0.f, 0.f);  // hbar accum
    // (per-thread slot: only this thread touches hjoint[4*tid..4*tid+3]
    //  until the epilogue barrier)

    // ------------- recurrence -------------
    float h_reg = 0.f, cbar = 0.f;
    float csum = 0.f, r_halt = 0.f;
    int   n_halt = 0;
    for (int t = 0; t <= MSTEPS; ++t) {
        // gate_lds valid here (pre-loop sync for t=0; bottom sync for t>0)
        float part = 0.f;
        float* hdst = (t & 1) ? hbuf1 : hbuf0;
        if (tid < JPB) {
            float iv = gate_lds[0 * JPB + tid];
            float fv = gate_lds[1 * JPB + tid];
            float gv = gate_lds[2 * JPB + tid];
            float ov = gate_lds[3 * JPB + tid];
            iv = 1.f / (1.f + expf(-iv));
            fv = 1.f / (1.f + expf(-fv));
            gv = tanhf(gv);
            ov = 1.f / (1.f + expf(-ov));
            c_reg = fv * c_reg + iv * gv;
            h_reg = ov * tanhf(c_reg);
            hdst[j_own] = h_reg;
            part = h_reg * whv;
        }
        part += __shfl_down(part, 4, 64);
        part += __shfl_down(part, 2, 64);
        part += __shfl_down(part, 1, 64);

        float dotv;
        SYNC_ROUND(t + 1, part, dotv);

        float p = 1.f / (1.f + expf(-(dotv + bh)));
        float prev = csum;
        csum += p;
        bool  halt_now = (csum >= 1.f - 0.01f) || (t == MSTEPS);
        float wt = halt_now ? (1.f - prev) : p;

        // full h_{t+1}: one read serves hbar accumulation AND hcur staging
        float4 hv = ((const float4*)hdst)[tid];
        float4 hb = ((float4*)hjoint)[tid];      // own slot, no race
        hb.x += wt * hv.x; hb.y += wt * hv.y;
        hb.z += wt * hv.z; hb.w += wt * hv.w;
        ((float4*)hjoint)[tid] = hb;
        if (tid < JPB) cbar += wt * c_reg;
        if (halt_now) { n_halt = t; r_halt = 1.f - prev; break; }  // uniform

        ((float4*)hcur)[tid] = hv;
        __syncthreads();                         // hcur ready

        {   // W_hh @ h : registers vs LDS, all fp32
            float m0 = 0.f, m1 = 0.f, m2 = 0.f, m3 = 0.f;
            DOT4((const float4*)hcur, m0, m1, m2, m3);
            m0 = wave_allreduce(m0); m1 = wave_allreduce(m1);
            m2 = wave_allreduce(m2); m3 = wave_allreduce(m3);
            if (lane < 4) {
                float mv = (lane == 0) ? m0 : (lane == 1) ? m1
                         : (lane == 2) ? m2 : m3;
                gate_lds[lr0 + lane] = ihx_lds[lr0 + lane] + mv;
            }
        }
        __syncthreads();                         // gate_lds ready for next t
    }

    // ------------- epilogue: no grid sync needed -------------
    __syncthreads();                             // hbar (hjoint) complete
    if (tid < JPB) {
        out[OUTS + j_own]       = hjoint[j_own];   // h_out
        out[OUTS + HID + j_own] = cbar;            // c_out
    }
    if (b == 0 && tid == 0) out[OUTS + 2 * HID] = (float)(n_halt + 1) + r_halt;

    // output = W_out @ hbar + b_out : W_out half-rows already in registers
    {
        const float4* hb4 = (const float4*)hjoint + ohalf * 256;
        float acc = 0.f;
        { float4 h4 = hb4[lane];       acc += wo0.x*h4.x + wo0.y*h4.y + wo0.z*h4.z + wo0.w*h4.w; }
        { float4 h4 = hb4[lane + 64];  acc += wo1.x*h4.x + wo1.y*h4.y + wo1.z*h4.z + wo1.w*h4.w; }
        { float4 h4 = hb4[lane + 128]; acc += wo2.x*h4.x + wo2.y*h4.y + wo2.z*h4.z + wo2.w*h4.w; }
        { float4 h4 = hb4[lane + 192]; acc += wo3.x*h4.x + wo3.y*h4.y + wo3.z*h4.z + wo3.w*h4.w; }
        acc = wave_allreduce(acc);
        if (lane == 0) psum[wave] = acc;
    }
    __syncthreads();
    if (tid < 4) out[b * 4 + tid] = psum[tid] + psum[tid + 4] + bo;

    #undef SYNC_ROUND
    #undef DOT4
}

extern "C" void kernel_launch(void* const* d_in, const int* in_sizes, int n_in,
                              void* d_out, int out_size, void* d_ws, size_t ws_size,
                              hipStream_t stream) {
    const float* x      = (const float*)d_in[0];
    const float* h0     = (const float*)d_in[1];
    const float* c0     = (const float*)d_in[2];
    const float* W_ih   = (const float*)d_in[3];
    const float* b_ih   = (const float*)d_in[4];
    const float* W_hh   = (const float*)d_in[5];
    const float* b_hh   = (const float*)d_in[6];
    const float* w_halt = (const float*)d_in[7];
    const float* b_halt = (const float*)d_in[8];
    const float* W_out  = (const float*)d_in[9];
    const float* b_out  = (const float*)d_in[10];
    float* out = (float*)d_out;
    float* ws  = (float*)d_ws;

    // Zero arrive slots + mailboxes (ws is poisoned 0xAA by the harness).
    hipMemsetAsync(d_ws, 0, 32768, stream);

    alstm_kernel<<<dim3(NBLK), dim3(NTHR), 0, stream>>>(
        x, h0, c0, W_ih, b_ih, W_hh, b_hh, w_halt, b_halt, W_out, b_out,
        out, ws);
}